// Round 13
// baseline (206.846 us; speedup 1.0000x reference)
//
#include <hip/hip_runtime.h>
#include <math.h>
#include <stdint.h>

#define B_   4
#define C_   256
#define H_   64
#define W_   64
#define CC_  64
#define OE_  196
#define OH_  128
#define OW_  128

typedef uint32_t u32;
typedef unsigned short u16;
typedef __attribute__((ext_vector_type(8))) short bf16x8;
typedef __attribute__((ext_vector_type(4))) float f32x4;
typedef __attribute__((ext_vector_type(4))) u32 u32x4;
typedef __attribute__((ext_vector_type(2))) u32 u32x2;

__device__ __forceinline__ u16 f2bf(float f) {
  u32 u = __builtin_bit_cast(u32, f);
  u32 r = (u + 0x7FFFu + ((u >> 16) & 1u)) >> 16;   // RNE
  return (u16)r;
}

// ------------------------------------------------------------------
// Kernel 0: weight re-layouts (tiny).
// ------------------------------------------------------------------
__global__ __launch_bounds__(256) void prep_weights(
    const float* __restrict__ w_comp, const float* __restrict__ w_enc,
    float* __restrict__ wct, u16* __restrict__ wfrag) {
  int idx = blockIdx.x * 256 + threadIdx.x;
  if (idx < 50 * 14 * 64) {
    int lane = idx & 63;
    int mt   = (idx >> 6) % 14;
    int ks   = idx / (14 * 64);
    int o    = mt * 16 + (lane & 15);
    int tap  = ks >> 1, s = ks & 1;
    int ky   = tap / 5, kx = tap % 5;
    int cb   = s * 32 + (lane >> 4) * 8;
    u32 pk[4];
    #pragma unroll
    for (int p = 0; p < 4; ++p) {
      u16 lo = 0, hi = 0;
      if (o < OE_) {
        lo = f2bf(w_enc[((o * CC_ + cb + 2 * p) * 5 + ky) * 5 + kx]);
        hi = f2bf(w_enc[((o * CC_ + cb + 2 * p + 1) * 5 + ky) * 5 + kx]);
      }
      pk[p] = (u32)lo | ((u32)hi << 16);
    }
    *reinterpret_cast<u32x4*>(wfrag + (size_t)idx * 8) =
        *reinterpret_cast<u32x4*>(pk);
  }
  if (idx < C_ * CC_) {
    int cc = idx / C_, c = idx % C_;
    wct[c * CC_ + cc] = w_comp[cc * C_ + c];
  }
}

// ------------------------------------------------------------------
// Kernel 1: 1x1 compressor — also emits xbf[b][h][w][c] bf16.
// ------------------------------------------------------------------
__global__ __launch_bounds__(256) void compress_k(
    const float* __restrict__ x, const float* __restrict__ wct,
    const float* __restrict__ b_comp, u16* __restrict__ comp,
    u16* __restrict__ xbf) {
  __shared__ float xs[C_ * 20];
  int t   = threadIdx.x;
  int gid = blockIdx.x;
  int wq  = gid & 3;
  int bh  = gid >> 2;
  int b = bh >> 6, h = bh & 63;
  int w0 = wq * 16;

  const float* xrow = x + (size_t)b * C_ * H_ * W_ + (size_t)h * W_ + w0;
  for (int i = t; i < 1024; i += 256) {
    int c = i >> 2, q = i & 3;
    f32x4 v = *reinterpret_cast<const f32x4*>(xrow + (size_t)c * H_ * W_ + q * 4);
    *reinterpret_cast<f32x4*>(xs + c * 20 + q * 4) = v;
  }
  __syncthreads();

  int w = t & 15, cq = t >> 4;   // cq 0..15 -> 4 cc each
  float acc[4] = {0.f, 0.f, 0.f, 0.f};
  for (int c = 0; c < C_; ++c) {
    float xv = xs[c * 20 + w];
    const float* wr = wct + c * CC_ + cq * 4;
    #pragma unroll
    for (int i = 0; i < 4; ++i) acc[i] = fmaf(xv, wr[i], acc[i]);
  }
  u32 pk[2];
  #pragma unroll
  for (int p = 0; p < 2; ++p) {
    u16 lo = f2bf(acc[2 * p]     + b_comp[cq * 4 + 2 * p]);
    u16 hi = f2bf(acc[2 * p + 1] + b_comp[cq * 4 + 2 * p + 1]);
    pk[p] = (u32)lo | ((u32)hi << 16);
  }
  *reinterpret_cast<u32x2*>(comp + ((size_t)bh * 64 + w0 + w) * CC_ + cq * 4) =
      *reinterpret_cast<u32x2*>(pk);

  // ---- xbf: thread (w,cq) packs channels cq*16..cq*16+15 ----
  {
    u32 px[8];
    #pragma unroll
    for (int i = 0; i < 8; ++i) {
      u16 lo = f2bf(xs[(cq * 16 + 2 * i) * 20 + w]);
      u16 hi = f2bf(xs[(cq * 16 + 2 * i + 1) * 20 + w]);
      px[i] = (u32)lo | ((u32)hi << 16);
    }
    u16* dst = xbf + ((size_t)bh * 64 + w0 + w) * C_ + cq * 16;
    reinterpret_cast<u32x4*>(dst)[0] = *reinterpret_cast<u32x4*>(px);
    reinterpret_cast<u32x4*>(dst)[1] = *reinterpret_cast<u32x4*>(px + 4);
  }
}

// ------------------------------------------------------------------
// Kernel 2: encoder MFMA GEMM v5 — N-split, barrier-free K-loop.
// Output smax is now bf16 [pixel][n*4+r].
// ------------------------------------------------------------------
#define ELG_ 32256   // 224*36*4

__device__ __forceinline__ void enc_lda(
    bf16x8 (&a)[4], const u16* __restrict__ wfrag,
    int ks, int mtbase, int mtcnt, int lane) {
  #pragma unroll
  for (int mm = 0; mm < 4; ++mm)
    if (mm < mtcnt)
      a[mm] = *reinterpret_cast<const bf16x8*>(
          wfrag + (((size_t)ks * 14 + mtbase + mm) * 64 + lane) * 8);
}

__device__ __forceinline__ void enc_step(
    int ks, const char* lds, const bf16x8 (&a)[4], f32x4 (&acc)[4][2],
    int nlane, int kq, int mtcnt) {
  int tap = ks >> 1, s = ks & 1;
  int ky = tap / 5, kx = tap % 5;
  bf16x8 bf[2];
  #pragma unroll
  for (int nt = 0; nt < 2; ++nt) {
    int col = nt * 16 + nlane + kx;
    int byte = (((ky * 36 + col) * 64 + s * 32 + kq * 8) * 2) ^ ((col & 7) << 4);
    bf[nt] = *reinterpret_cast<const bf16x8*>(lds + byte);
  }
  #pragma unroll
  for (int mm = 0; mm < 4; ++mm) {
    if (mm < mtcnt) {
      #pragma unroll
      for (int nt = 0; nt < 2; ++nt)
        acc[mm][nt] = __builtin_amdgcn_mfma_f32_16x16x32_bf16(
            a[mm], bf[nt], acc[mm][nt], 0, 0, 0);
    }
  }
}

__global__ __launch_bounds__(256) void enc_mfma_k(
    const u16* __restrict__ comp, const u16* __restrict__ wfrag,
    const float* __restrict__ b_enc, u16* __restrict__ smax) {
  __shared__ __align__(16) char lds[ELG_];

  int t   = threadIdx.x;
  int bid = blockIdx.x;
  int swz = (bid & 7) * 64 + (bid >> 3);   // 512 blocks, bijective
  int wh  = swz & 1;
  int bh  = swz >> 1;
  int b = bh >> 6, h = bh & 63;
  int w0 = wh * 32;

  // ---- stage B tile: 5 rows x 36 cols x 64 ch, XOR-swizzled ----
  {
    const u16* cbse = comp + (size_t)b * H_ * W_ * CC_;
    for (int i = t; i < 1440; i += 256) {
      int q = i & 7, colr = i >> 3;
      int col = colr % 36, r = colr / 36;
      int hh = h - 2 + r, gw = w0 - 2 + col;
      u32x4 v = {0, 0, 0, 0};
      if ((unsigned)hh < H_ && (unsigned)gw < W_)
        v = *reinterpret_cast<const u32x4*>(cbse + ((size_t)hh * W_ + gw) * CC_ + q * 8);
      int byte = ((r * 36 + col) * 128 + q * 16) ^ ((col & 7) << 4);
      *reinterpret_cast<u32x4*>(lds + byte) = v;
    }
  }
  __syncthreads();   // B ready; no further barriers in K-loop

  int wv    = __builtin_amdgcn_readfirstlane(t >> 6);
  int lane  = t & 63;
  int nlane = lane & 15, kq = lane >> 4;
  int mtbase = (wv < 2) ? wv * 4 : 3 * wv + 2;   // {0,4,8,11}
  int mtcnt  = (wv < 2) ? 4 : 3;

  f32x4 acc[4][2];
  #pragma unroll
  for (int mm = 0; mm < 4; ++mm)
    #pragma unroll
    for (int nt = 0; nt < 2; ++nt) acc[mm][nt] = (f32x4){0.f, 0.f, 0.f, 0.f};

  bf16x8 aA[4], aB[4];
  enc_lda(aA, wfrag, 0, mtbase, mtcnt, lane);
  enc_lda(aB, wfrag, 1, mtbase, mtcnt, lane);
  for (int ks = 0; ks + 2 < 50; ks += 2) {
    enc_step(ks, lds, aA, acc, nlane, kq, mtcnt);
    enc_lda(aA, wfrag, ks + 2, mtbase, mtcnt, lane);
    enc_step(ks + 1, lds, aB, acc, nlane, kq, mtcnt);
    enc_lda(aB, wfrag, ks + 3, mtbase, mtcnt, lane);
  }
  enc_step(48, lds, aA, acc, nlane, kq, mtcnt);
  enc_step(49, lds, aB, acc, nlane, kq, mtcnt);

  // ---- epilogue: logits -> LDS [224][36] f32, fused softmax ----
  __syncthreads();
  float* lg = (float*)lds;
  #pragma unroll
  for (int mm = 0; mm < 4; ++mm) {
    if (mm < mtcnt) {
      #pragma unroll
      for (int nt = 0; nt < 2; ++nt) {
        #pragma unroll
        for (int r = 0; r < 4; ++r) {
          int m  = (mtbase + mm) * 16 + kq * 4 + r;
          int px = nt * 16 + nlane;
          lg[m * 36 + px] = acc[mm][nt][r] + (m < OE_ ? b_enc[m] : 0.f);
        }
      }
    }
  }
  __syncthreads();

  if (t < 128) {
    int px = t & 31, rr = t >> 5;
    float v[49];
    float mx = -1e30f;
    #pragma unroll
    for (int n = 0; n < 49; ++n) {
      v[n] = lg[(4 * n + rr) * 36 + px];
      mx = fmaxf(mx, v[n]);
    }
    float sum = 0.f;
    #pragma unroll
    for (int n = 0; n < 49; ++n) { v[n] = __expf(v[n] - mx); sum += v[n]; }
    float inv = 1.f / sum;
    u16* so = smax + ((size_t)bh * 64 + w0 + px) * OE_;
    #pragma unroll
    for (int n = 0; n < 49; ++n) so[n * 4 + rr] = f2bf(v[n] * inv);   // [n][r] bf16
  }
}

// ------------------------------------------------------------------
// Kernel 3: CARAFE v13 — 512-thread blocks, thread = (w, 4ch).
// Same tile as v11 (b, 2h, 8w, 256ch): xs bf16 [8][14][256] swizzled
// (57.3KB) + ssm bf16 [2][8][200] (6.4KB) = 63.7KB -> 2 blocks/CU
// = 16 waves/CU.  acc = 32 f32, xv batch = 7 x b64 (14 VGPR):
// ~85 VGPR total, no spill.  sv reads are 8-way broadcasts.
// ------------------------------------------------------------------
__global__ __launch_bounds__(512) void carafe_k(
    const u16* __restrict__ xbf, const u16* __restrict__ smax,
    float* __restrict__ out) {
  __shared__ __align__(16) u16 xs[8 * 14 * 256];   // 57,344 B
  __shared__ __align__(16) u16 ssm[2 * 8 * 200];   //  6,400 B
  int t   = threadIdx.x;                            // 0..511
  int bid = blockIdx.x;
  int swz = (bid & 7) * 128 + (bid >> 3);   // 1024 blocks, bijective
  int wq  = swz & 7;
  int hp  = (swz >> 3) & 31;
  int b   = swz >> 8;
  int w0 = wq * 8, h0 = hp * 2;

  // ---- stage xs: 8 rows x 14 j x 32 slots (8 ch each), swizzled ----
  {
    const u16* xb = xbf + (size_t)b * H_ * W_ * C_;
    #pragma unroll
    for (int it = 0; it < 7; ++it) {
      int idx  = it * 512 + t;          // 0..3583
      int slot = idx & 31;
      int j    = (idx >> 5) % 14;
      int row  = idx / 448;
      int gh = h0 - 3 + row, gw = w0 - 3 + j;
      u32x4 v = {0, 0, 0, 0};
      if ((unsigned)gh < H_ && (unsigned)gw < W_)
        v = *reinterpret_cast<const u32x4*>(xb + ((gh * W_ + gw) * C_ + slot * 8));
      int dst = row * 3584 + j * 256 + ((slot ^ (j & 7)) * 8);
      *reinterpret_cast<u32x4*>(xs + dst) = v;
    }
  }
  // ---- stage ssm (bf16 copy): 2 h x 8 w x 49 quads ----
  for (int idx = t; idx < 784; idx += 512) {
    int n4 = idx % 49;
    int wv = (idx / 49) & 7;
    int hs = idx / 392;
    const u16* sp = smax +
        ((size_t)((b * H_ + h0 + hs) * W_) + w0 + wv) * OE_ + n4 * 4;
    *reinterpret_cast<u32x2*>(ssm + (hs * 8 + wv) * 200 + n4 * 4) =
        *reinterpret_cast<const u32x2*>(sp);
  }
  __syncthreads();

  int w = t & 7, g4 = t >> 3;        // g4 0..63 -> 4 channels
  int slot = g4 >> 1, sub = g4 & 1;
  const u16* s0base = ssm + w * 200;          // hs = 0
  const u16* s1base = ssm + 1600 + w * 200;   // hs = 1
  f32x4 acc0[4], acc1[4];
  #pragma unroll
  for (int ci = 0; ci < 4; ++ci) {
    acc0[ci] = (f32x4){0.f, 0.f, 0.f, 0.f};
    acc1[ci] = (f32x4){0.f, 0.f, 0.f, 0.f};
  }

  #pragma unroll
  for (int row = 0; row < 8; ++row) {
    // batch: 7 xv b64 reads issued back-to-back (4 ch bf16 each)
    u32x2 xvb[7];
    #pragma unroll
    for (int dx = 0; dx < 7; ++dx) {
      int j = w + dx;
      xvb[dx] = *reinterpret_cast<const u32x2*>(
          xs + row * 3584 + j * 256 + ((slot ^ (j & 7)) * 8) + sub * 4);
    }
    #pragma unroll
    for (int dx = 0; dx < 7; ++dx) {
      float xf[4];
      #pragma unroll
      for (int k = 0; k < 2; ++k) {
        xf[2 * k]     = __builtin_bit_cast(float, xvb[dx][k] << 16);
        xf[2 * k + 1] = __builtin_bit_cast(float, xvb[dx][k] & 0xffff0000u);
      }
      if (row < 7) {   // hs=0, dy=row
        u32x2 sp = *reinterpret_cast<const u32x2*>(s0base + (row * 7 + dx) * 4);
        f32x4 s0 = {__builtin_bit_cast(float, sp[0] << 16),
                    __builtin_bit_cast(float, sp[0] & 0xffff0000u),
                    __builtin_bit_cast(float, sp[1] << 16),
                    __builtin_bit_cast(float, sp[1] & 0xffff0000u)};
        #pragma unroll
        for (int ci = 0; ci < 4; ++ci) {
          acc0[ci][0] = fmaf(xf[ci], s0[0], acc0[ci][0]);
          acc0[ci][1] = fmaf(xf[ci], s0[1], acc0[ci][1]);
          acc0[ci][2] = fmaf(xf[ci], s0[2], acc0[ci][2]);
          acc0[ci][3] = fmaf(xf[ci], s0[3], acc0[ci][3]);
        }
      }
      if (row >= 1) {  // hs=1, dy=row-1
        u32x2 sp = *reinterpret_cast<const u32x2*>(s1base + ((row - 1) * 7 + dx) * 4);
        f32x4 s1 = {__builtin_bit_cast(float, sp[0] << 16),
                    __builtin_bit_cast(float, sp[0] & 0xffff0000u),
                    __builtin_bit_cast(float, sp[1] << 16),
                    __builtin_bit_cast(float, sp[1] & 0xffff0000u)};
        #pragma unroll
        for (int ci = 0; ci < 4; ++ci) {
          acc1[ci][0] = fmaf(xf[ci], s1[0], acc1[ci][0]);
          acc1[ci][1] = fmaf(xf[ci], s1[1], acc1[ci][1]);
          acc1[ci][2] = fmaf(xf[ci], s1[2], acc1[ci][2]);
          acc1[ci][3] = fmaf(xf[ci], s1[3], acc1[ci][3]);
        }
      }
    }
  }

  #pragma unroll
  for (int ci = 0; ci < 4; ++ci) {
    int c = g4 * 4 + ci;
    float* base = out + ((size_t)(b * C_ + c) * OH_ + 2 * h0) * OW_ + 2 * (w0 + w);
    *reinterpret_cast<float2*>(base)            = make_float2(acc0[ci][0], acc0[ci][1]);
    *reinterpret_cast<float2*>(base + OW_)      = make_float2(acc0[ci][2], acc0[ci][3]);
    *reinterpret_cast<float2*>(base + 2 * OW_)  = make_float2(acc1[ci][0], acc1[ci][1]);
    *reinterpret_cast<float2*>(base + 3 * OW_)  = make_float2(acc1[ci][2], acc1[ci][3]);
  }
}

// ------------------------------------------------------------------
extern "C" void kernel_launch(void* const* d_in, const int* in_sizes, int n_in,
                              void* d_out, int out_size, void* d_ws, size_t ws_size,
                              hipStream_t stream) {
  const float* x      = (const float*)d_in[0];
  const float* w_comp = (const float*)d_in[1];
  const float* b_comp = (const float*)d_in[2];
  const float* w_enc  = (const float*)d_in[3];
  const float* b_enc  = (const float*)d_in[4];
  float* out = (float*)d_out;

  float* wct = (float*)d_ws;                    //    16,384 f32
  u16* smax  = (u16*)(wct + 16384);             // 3,211,264 bf16
  u16* wfrag = smax + 3211264;                  //   358,400 bf16
  u16* comp  = wfrag + 358400;                  // 1,048,576 bf16
  u16* xbf   = comp + 1048576;                  // 4,194,304 bf16 (~17.7MB total)

  prep_weights<<<175, 256, 0, stream>>>(w_comp, w_enc, wct, wfrag);
  compress_k<<<B_ * H_ * 4, 256, 0, stream>>>(x, wct, b_comp, comp, xbf);
  enc_mfma_k<<<512, 256, 0, stream>>>(comp, wfrag, b_enc, smax);
  carafe_k<<<1024, 512, 0, stream>>>(xbf, smax, out);
}

// Round 14
// 140.824 us; speedup vs baseline: 1.4688x; 1.4688x over previous
//
#include <hip/hip_runtime.h>
#include <math.h>
#include <stdint.h>

#define B_   4
#define C_   256
#define H_   64
#define W_   64
#define CC_  64
#define OE_  196
#define OH_  128
#define OW_  128

typedef uint32_t u32;
typedef unsigned short u16;
typedef __attribute__((ext_vector_type(8))) short bf16x8;
typedef __attribute__((ext_vector_type(4))) float f32x4;
typedef __attribute__((ext_vector_type(4))) u32 u32x4;
typedef __attribute__((ext_vector_type(2))) u32 u32x2;

__device__ __forceinline__ u16 f2bf(float f) {
  u32 u = __builtin_bit_cast(u32, f);
  u32 r = (u + 0x7FFFu + ((u >> 16) & 1u)) >> 16;   // RNE
  return (u16)r;
}

// ------------------------------------------------------------------
// Kernel 0: weight re-layouts (tiny).
// ------------------------------------------------------------------
__global__ __launch_bounds__(256) void prep_weights(
    const float* __restrict__ w_comp, const float* __restrict__ w_enc,
    float* __restrict__ wct, u16* __restrict__ wfrag) {
  int idx = blockIdx.x * 256 + threadIdx.x;
  if (idx < 50 * 14 * 64) {
    int lane = idx & 63;
    int mt   = (idx >> 6) % 14;
    int ks   = idx / (14 * 64);
    int o    = mt * 16 + (lane & 15);
    int tap  = ks >> 1, s = ks & 1;
    int ky   = tap / 5, kx = tap % 5;
    int cb   = s * 32 + (lane >> 4) * 8;
    u32 pk[4];
    #pragma unroll
    for (int p = 0; p < 4; ++p) {
      u16 lo = 0, hi = 0;
      if (o < OE_) {
        lo = f2bf(w_enc[((o * CC_ + cb + 2 * p) * 5 + ky) * 5 + kx]);
        hi = f2bf(w_enc[((o * CC_ + cb + 2 * p + 1) * 5 + ky) * 5 + kx]);
      }
      pk[p] = (u32)lo | ((u32)hi << 16);
    }
    *reinterpret_cast<u32x4*>(wfrag + (size_t)idx * 8) =
        *reinterpret_cast<u32x4*>(pk);
  }
  if (idx < C_ * CC_) {
    int cc = idx / C_, c = idx % C_;
    wct[c * CC_ + cc] = w_comp[cc * C_ + c];
  }
}

// ------------------------------------------------------------------
// Kernel 1: 1x1 compressor — also emits xbf[b][h][w][c] bf16.
// ------------------------------------------------------------------
__global__ __launch_bounds__(256) void compress_k(
    const float* __restrict__ x, const float* __restrict__ wct,
    const float* __restrict__ b_comp, u16* __restrict__ comp,
    u16* __restrict__ xbf) {
  __shared__ float xs[C_ * 20];
  int t   = threadIdx.x;
  int gid = blockIdx.x;
  int wq  = gid & 3;
  int bh  = gid >> 2;
  int b = bh >> 6, h = bh & 63;
  int w0 = wq * 16;

  const float* xrow = x + (size_t)b * C_ * H_ * W_ + (size_t)h * W_ + w0;
  for (int i = t; i < 1024; i += 256) {
    int c = i >> 2, q = i & 3;
    f32x4 v = *reinterpret_cast<const f32x4*>(xrow + (size_t)c * H_ * W_ + q * 4);
    *reinterpret_cast<f32x4*>(xs + c * 20 + q * 4) = v;
  }
  __syncthreads();

  int w = t & 15, cq = t >> 4;   // cq 0..15 -> 4 cc each
  float acc[4] = {0.f, 0.f, 0.f, 0.f};
  for (int c = 0; c < C_; ++c) {
    float xv = xs[c * 20 + w];
    const float* wr = wct + c * CC_ + cq * 4;
    #pragma unroll
    for (int i = 0; i < 4; ++i) acc[i] = fmaf(xv, wr[i], acc[i]);
  }
  u32 pk[2];
  #pragma unroll
  for (int p = 0; p < 2; ++p) {
    u16 lo = f2bf(acc[2 * p]     + b_comp[cq * 4 + 2 * p]);
    u16 hi = f2bf(acc[2 * p + 1] + b_comp[cq * 4 + 2 * p + 1]);
    pk[p] = (u32)lo | ((u32)hi << 16);
  }
  *reinterpret_cast<u32x2*>(comp + ((size_t)bh * 64 + w0 + w) * CC_ + cq * 4) =
      *reinterpret_cast<u32x2*>(pk);

  // ---- xbf: thread (w,cq) packs channels cq*16..cq*16+15 ----
  {
    u32 px[8];
    #pragma unroll
    for (int i = 0; i < 8; ++i) {
      u16 lo = f2bf(xs[(cq * 16 + 2 * i) * 20 + w]);
      u16 hi = f2bf(xs[(cq * 16 + 2 * i + 1) * 20 + w]);
      px[i] = (u32)lo | ((u32)hi << 16);
    }
    u16* dst = xbf + ((size_t)bh * 64 + w0 + w) * C_ + cq * 16;
    reinterpret_cast<u32x4*>(dst)[0] = *reinterpret_cast<u32x4*>(px);
    reinterpret_cast<u32x4*>(dst)[1] = *reinterpret_cast<u32x4*>(px + 4);
  }
}

// ------------------------------------------------------------------
// Kernel 2: encoder MFMA GEMM v5 — N-split, barrier-free K-loop.
// Output smax bf16 [pixel][n*4+r].  (unchanged from R13)
// ------------------------------------------------------------------
#define ELG_ 32256   // 224*36*4

__device__ __forceinline__ void enc_lda(
    bf16x8 (&a)[4], const u16* __restrict__ wfrag,
    int ks, int mtbase, int mtcnt, int lane) {
  #pragma unroll
  for (int mm = 0; mm < 4; ++mm)
    if (mm < mtcnt)
      a[mm] = *reinterpret_cast<const bf16x8*>(
          wfrag + (((size_t)ks * 14 + mtbase + mm) * 64 + lane) * 8);
}

__device__ __forceinline__ void enc_step(
    int ks, const char* lds, const bf16x8 (&a)[4], f32x4 (&acc)[4][2],
    int nlane, int kq, int mtcnt) {
  int tap = ks >> 1, s = ks & 1;
  int ky = tap / 5, kx = tap % 5;
  bf16x8 bf[2];
  #pragma unroll
  for (int nt = 0; nt < 2; ++nt) {
    int col = nt * 16 + nlane + kx;
    int byte = (((ky * 36 + col) * 64 + s * 32 + kq * 8) * 2) ^ ((col & 7) << 4);
    bf[nt] = *reinterpret_cast<const bf16x8*>(lds + byte);
  }
  #pragma unroll
  for (int mm = 0; mm < 4; ++mm) {
    if (mm < mtcnt) {
      #pragma unroll
      for (int nt = 0; nt < 2; ++nt)
        acc[mm][nt] = __builtin_amdgcn_mfma_f32_16x16x32_bf16(
            a[mm], bf[nt], acc[mm][nt], 0, 0, 0);
    }
  }
}

__global__ __launch_bounds__(256) void enc_mfma_k(
    const u16* __restrict__ comp, const u16* __restrict__ wfrag,
    const float* __restrict__ b_enc, u16* __restrict__ smax) {
  __shared__ __align__(16) char lds[ELG_];

  int t   = threadIdx.x;
  int bid = blockIdx.x;
  int swz = (bid & 7) * 64 + (bid >> 3);   // 512 blocks, bijective
  int wh  = swz & 1;
  int bh  = swz >> 1;
  int b = bh >> 6, h = bh & 63;
  int w0 = wh * 32;

  // ---- stage B tile: 5 rows x 36 cols x 64 ch, XOR-swizzled ----
  {
    const u16* cbse = comp + (size_t)b * H_ * W_ * CC_;
    for (int i = t; i < 1440; i += 256) {
      int q = i & 7, colr = i >> 3;
      int col = colr % 36, r = colr / 36;
      int hh = h - 2 + r, gw = w0 - 2 + col;
      u32x4 v = {0, 0, 0, 0};
      if ((unsigned)hh < H_ && (unsigned)gw < W_)
        v = *reinterpret_cast<const u32x4*>(cbse + ((size_t)hh * W_ + gw) * CC_ + q * 8);
      int byte = ((r * 36 + col) * 128 + q * 16) ^ ((col & 7) << 4);
      *reinterpret_cast<u32x4*>(lds + byte) = v;
    }
  }
  __syncthreads();   // B ready; no further barriers in K-loop

  int wv    = __builtin_amdgcn_readfirstlane(t >> 6);
  int lane  = t & 63;
  int nlane = lane & 15, kq = lane >> 4;
  int mtbase = (wv < 2) ? wv * 4 : 3 * wv + 2;   // {0,4,8,11}
  int mtcnt  = (wv < 2) ? 4 : 3;

  f32x4 acc[4][2];
  #pragma unroll
  for (int mm = 0; mm < 4; ++mm)
    #pragma unroll
    for (int nt = 0; nt < 2; ++nt) acc[mm][nt] = (f32x4){0.f, 0.f, 0.f, 0.f};

  bf16x8 aA[4], aB[4];
  enc_lda(aA, wfrag, 0, mtbase, mtcnt, lane);
  enc_lda(aB, wfrag, 1, mtbase, mtcnt, lane);
  for (int ks = 0; ks + 2 < 50; ks += 2) {
    enc_step(ks, lds, aA, acc, nlane, kq, mtcnt);
    enc_lda(aA, wfrag, ks + 2, mtbase, mtcnt, lane);
    enc_step(ks + 1, lds, aB, acc, nlane, kq, mtcnt);
    enc_lda(aB, wfrag, ks + 3, mtbase, mtcnt, lane);
  }
  enc_step(48, lds, aA, acc, nlane, kq, mtcnt);
  enc_step(49, lds, aB, acc, nlane, kq, mtcnt);

  // ---- epilogue: logits -> LDS [224][36] f32, fused softmax ----
  __syncthreads();
  float* lg = (float*)lds;
  #pragma unroll
  for (int mm = 0; mm < 4; ++mm) {
    if (mm < mtcnt) {
      #pragma unroll
      for (int nt = 0; nt < 2; ++nt) {
        #pragma unroll
        for (int r = 0; r < 4; ++r) {
          int m  = (mtbase + mm) * 16 + kq * 4 + r;
          int px = nt * 16 + nlane;
          lg[m * 36 + px] = acc[mm][nt][r] + (m < OE_ ? b_enc[m] : 0.f);
        }
      }
    }
  }
  __syncthreads();

  if (t < 128) {
    int px = t & 31, rr = t >> 5;
    float v[49];
    float mx = -1e30f;
    #pragma unroll
    for (int n = 0; n < 49; ++n) {
      v[n] = lg[(4 * n + rr) * 36 + px];
      mx = fmaxf(mx, v[n]);
    }
    float sum = 0.f;
    #pragma unroll
    for (int n = 0; n < 49; ++n) { v[n] = __expf(v[n] - mx); sum += v[n]; }
    float inv = 1.f / sum;
    u16* so = smax + ((size_t)bh * 64 + w0 + px) * OE_;
    #pragma unroll
    for (int n = 0; n < 49; ++n) so[n * 4 + rr] = f2bf(v[n] * inv);   // [n][r] bf16
  }
}

// ------------------------------------------------------------------
// Kernel 3: CARAFE v14 — ZERO-LDS, zero-barrier L2 streaming.
// Thread = (pixel, 8-ch group): block = 8 pixels x 32 ch-groups.
// Per tap: 1 global b128 xv (8 bf16 ch, coalesced 512B/wave) +
// 1 global b64 sv (32-lane broadcast) + 32 FMA.  acc = 32 f32,
// no batch arrays, no LDS -> VGPR ~60, occupancy VGPR-bound only
// (8 waves/SIMD hides L2 latency).  XCD swizzle: each XCD gets a
// contiguous 32-h-row slice of one b (x ~1MB + smax 0.8MB L2-hot).
// ------------------------------------------------------------------
__global__ __launch_bounds__(256) void carafe_k(
    const u16* __restrict__ xbf, const u16* __restrict__ smax,
    float* __restrict__ out) {
  int t   = threadIdx.x;
  int bid = blockIdx.x;                      // 2048 blocks
  int pg  = (bid & 7) * 256 + (bid >> 3);    // bijective XCD chunk
  int wq  = pg & 7;
  int h   = (pg >> 3) & 63;
  int b   = pg >> 9;
  int w0  = wq * 8;

  int cg  = t & 31;          // channel group: c = cg*8 .. cg*8+7
  int pix = t >> 5;          // 0..7
  int w   = w0 + pix;

  const u16* sp = smax + ((size_t)((b * 64 + h) * 64) + w) * OE_;
  const u16* xb = xbf + (size_t)b * H_ * W_ * C_ + cg * 8;

  f32x4 acc[8];
  #pragma unroll
  for (int ci = 0; ci < 8; ++ci) acc[ci] = (f32x4){0.f, 0.f, 0.f, 0.f};

  #pragma unroll
  for (int dy = 0; dy < 7; ++dy) {
    int gh = h - 3 + dy;
    bool vr = (unsigned)gh < H_;
    const u16* xrow = xb + (size_t)gh * W_ * C_;
    #pragma unroll
    for (int dx = 0; dx < 7; ++dx) {
      int gw = w - 3 + dx;
      u32x4 xv = {0, 0, 0, 0};
      if (vr && (unsigned)gw < W_)
        xv = *reinterpret_cast<const u32x4*>(xrow + gw * C_);
      u32x2 sv2 = *reinterpret_cast<const u32x2*>(sp + (dy * 7 + dx) * 4);
      f32x4 sv = {__builtin_bit_cast(float, sv2[0] << 16),
                  __builtin_bit_cast(float, sv2[0] & 0xffff0000u),
                  __builtin_bit_cast(float, sv2[1] << 16),
                  __builtin_bit_cast(float, sv2[1] & 0xffff0000u)};
      float xf[8];
      #pragma unroll
      for (int k = 0; k < 4; ++k) {
        xf[2 * k]     = __builtin_bit_cast(float, xv[k] << 16);
        xf[2 * k + 1] = __builtin_bit_cast(float, xv[k] & 0xffff0000u);
      }
      #pragma unroll
      for (int ci = 0; ci < 8; ++ci) {
        acc[ci][0] = fmaf(xf[ci], sv[0], acc[ci][0]);
        acc[ci][1] = fmaf(xf[ci], sv[1], acc[ci][1]);
        acc[ci][2] = fmaf(xf[ci], sv[2], acc[ci][2]);
        acc[ci][3] = fmaf(xf[ci], sv[3], acc[ci][3]);
      }
    }
  }

  #pragma unroll
  for (int ci = 0; ci < 8; ++ci) {
    int c = cg * 8 + ci;
    float* base = out + ((size_t)(b * C_ + c) * OH_ + 2 * h) * OW_ + 2 * w;
    *reinterpret_cast<float2*>(base)       = make_float2(acc[ci][0], acc[ci][1]);
    *reinterpret_cast<float2*>(base + OW_) = make_float2(acc[ci][2], acc[ci][3]);
  }
}

// ------------------------------------------------------------------
extern "C" void kernel_launch(void* const* d_in, const int* in_sizes, int n_in,
                              void* d_out, int out_size, void* d_ws, size_t ws_size,
                              hipStream_t stream) {
  const float* x      = (const float*)d_in[0];
  const float* w_comp = (const float*)d_in[1];
  const float* b_comp = (const float*)d_in[2];
  const float* w_enc  = (const float*)d_in[3];
  const float* b_enc  = (const float*)d_in[4];
  float* out = (float*)d_out;

  float* wct = (float*)d_ws;                    //    16,384 f32
  u16* smax  = (u16*)(wct + 16384);             // 3,211,264 bf16
  u16* wfrag = smax + 3211264;                  //   358,400 bf16
  u16* comp  = wfrag + 358400;                  // 1,048,576 bf16
  u16* xbf   = comp + 1048576;                  // 4,194,304 bf16 (~17.7MB total)

  prep_weights<<<175, 256, 0, stream>>>(w_comp, w_enc, wct, wfrag);
  compress_k<<<B_ * H_ * 4, 256, 0, stream>>>(x, wct, b_comp, comp, xbf);
  enc_mfma_k<<<512, 256, 0, stream>>>(comp, wfrag, b_enc, smax);
  carafe_k<<<2048, 256, 0, stream>>>(xbf, smax, out);
}

// Round 15
// 117.988 us; speedup vs baseline: 1.7531x; 1.1936x over previous
//
#include <hip/hip_runtime.h>
#include <math.h>
#include <stdint.h>

#define B_   4
#define C_   256
#define H_   64
#define W_   64
#define CC_  64
#define OE_  196
#define OH_  128
#define OW_  128

typedef uint32_t u32;
typedef unsigned short u16;
typedef __attribute__((ext_vector_type(8))) short bf16x8;
typedef __attribute__((ext_vector_type(4))) float f32x4;
typedef __attribute__((ext_vector_type(4))) u32 u32x4;
typedef __attribute__((ext_vector_type(2))) u32 u32x2;

__device__ __forceinline__ u16 f2bf(float f) {
  u32 u = __builtin_bit_cast(u32, f);
  u32 r = (u + 0x7FFFu + ((u >> 16) & 1u)) >> 16;   // RNE
  return (u16)r;
}

// ------------------------------------------------------------------
// Kernel 0: weight re-layouts (tiny).
// ------------------------------------------------------------------
__global__ __launch_bounds__(256) void prep_weights(
    const float* __restrict__ w_comp, const float* __restrict__ w_enc,
    float* __restrict__ wct, u16* __restrict__ wfrag) {
  int idx = blockIdx.x * 256 + threadIdx.x;
  if (idx < 50 * 14 * 64) {
    int lane = idx & 63;
    int mt   = (idx >> 6) % 14;
    int ks   = idx / (14 * 64);
    int o    = mt * 16 + (lane & 15);
    int tap  = ks >> 1, s = ks & 1;
    int ky   = tap / 5, kx = tap % 5;
    int cb   = s * 32 + (lane >> 4) * 8;
    u32 pk[4];
    #pragma unroll
    for (int p = 0; p < 4; ++p) {
      u16 lo = 0, hi = 0;
      if (o < OE_) {
        lo = f2bf(w_enc[((o * CC_ + cb + 2 * p) * 5 + ky) * 5 + kx]);
        hi = f2bf(w_enc[((o * CC_ + cb + 2 * p + 1) * 5 + ky) * 5 + kx]);
      }
      pk[p] = (u32)lo | ((u32)hi << 16);
    }
    *reinterpret_cast<u32x4*>(wfrag + (size_t)idx * 8) =
        *reinterpret_cast<u32x4*>(pk);
  }
  if (idx < C_ * CC_) {
    int cc = idx / C_, c = idx % C_;
    wct[c * CC_ + cc] = w_comp[cc * C_ + c];
  }
}

// ------------------------------------------------------------------
// Kernel 1: 1x1 compressor — also emits xbf[b][h][w][c] bf16.
// ------------------------------------------------------------------
__global__ __launch_bounds__(256) void compress_k(
    const float* __restrict__ x, const float* __restrict__ wct,
    const float* __restrict__ b_comp, u16* __restrict__ comp,
    u16* __restrict__ xbf) {
  __shared__ float xs[C_ * 20];
  int t   = threadIdx.x;
  int gid = blockIdx.x;
  int wq  = gid & 3;
  int bh  = gid >> 2;
  int b = bh >> 6, h = bh & 63;
  int w0 = wq * 16;

  const float* xrow = x + (size_t)b * C_ * H_ * W_ + (size_t)h * W_ + w0;
  for (int i = t; i < 1024; i += 256) {
    int c = i >> 2, q = i & 3;
    f32x4 v = *reinterpret_cast<const f32x4*>(xrow + (size_t)c * H_ * W_ + q * 4);
    *reinterpret_cast<f32x4*>(xs + c * 20 + q * 4) = v;
  }
  __syncthreads();

  int w = t & 15, cq = t >> 4;   // cq 0..15 -> 4 cc each
  float acc[4] = {0.f, 0.f, 0.f, 0.f};
  for (int c = 0; c < C_; ++c) {
    float xv = xs[c * 20 + w];
    const float* wr = wct + c * CC_ + cq * 4;
    #pragma unroll
    for (int i = 0; i < 4; ++i) acc[i] = fmaf(xv, wr[i], acc[i]);
  }
  u32 pk[2];
  #pragma unroll
  for (int p = 0; p < 2; ++p) {
    u16 lo = f2bf(acc[2 * p]     + b_comp[cq * 4 + 2 * p]);
    u16 hi = f2bf(acc[2 * p + 1] + b_comp[cq * 4 + 2 * p + 1]);
    pk[p] = (u32)lo | ((u32)hi << 16);
  }
  *reinterpret_cast<u32x2*>(comp + ((size_t)bh * 64 + w0 + w) * CC_ + cq * 4) =
      *reinterpret_cast<u32x2*>(pk);

  // ---- xbf: thread (w,cq) packs channels cq*16..cq*16+15 ----
  {
    u32 px[8];
    #pragma unroll
    for (int i = 0; i < 8; ++i) {
      u16 lo = f2bf(xs[(cq * 16 + 2 * i) * 20 + w]);
      u16 hi = f2bf(xs[(cq * 16 + 2 * i + 1) * 20 + w]);
      px[i] = (u32)lo | ((u32)hi << 16);
    }
    u16* dst = xbf + ((size_t)bh * 64 + w0 + w) * C_ + cq * 16;
    reinterpret_cast<u32x4*>(dst)[0] = *reinterpret_cast<u32x4*>(px);
    reinterpret_cast<u32x4*>(dst)[1] = *reinterpret_cast<u32x4*>(px + 4);
  }
}

// ------------------------------------------------------------------
// Kernel 2: encoder MFMA GEMM v5 — N-split, barrier-free K-loop.
// Output smax bf16 [pixel][n*4+r].  (unchanged)
// ------------------------------------------------------------------
#define ELG_ 32256   // 224*36*4

__device__ __forceinline__ void enc_lda(
    bf16x8 (&a)[4], const u16* __restrict__ wfrag,
    int ks, int mtbase, int mtcnt, int lane) {
  #pragma unroll
  for (int mm = 0; mm < 4; ++mm)
    if (mm < mtcnt)
      a[mm] = *reinterpret_cast<const bf16x8*>(
          wfrag + (((size_t)ks * 14 + mtbase + mm) * 64 + lane) * 8);
}

__device__ __forceinline__ void enc_step(
    int ks, const char* lds, const bf16x8 (&a)[4], f32x4 (&acc)[4][2],
    int nlane, int kq, int mtcnt) {
  int tap = ks >> 1, s = ks & 1;
  int ky = tap / 5, kx = tap % 5;
  bf16x8 bf[2];
  #pragma unroll
  for (int nt = 0; nt < 2; ++nt) {
    int col = nt * 16 + nlane + kx;
    int byte = (((ky * 36 + col) * 64 + s * 32 + kq * 8) * 2) ^ ((col & 7) << 4);
    bf[nt] = *reinterpret_cast<const bf16x8*>(lds + byte);
  }
  #pragma unroll
  for (int mm = 0; mm < 4; ++mm) {
    if (mm < mtcnt) {
      #pragma unroll
      for (int nt = 0; nt < 2; ++nt)
        acc[mm][nt] = __builtin_amdgcn_mfma_f32_16x16x32_bf16(
            a[mm], bf[nt], acc[mm][nt], 0, 0, 0);
    }
  }
}

__global__ __launch_bounds__(256) void enc_mfma_k(
    const u16* __restrict__ comp, const u16* __restrict__ wfrag,
    const float* __restrict__ b_enc, u16* __restrict__ smax) {
  __shared__ __align__(16) char lds[ELG_];

  int t   = threadIdx.x;
  int bid = blockIdx.x;
  int swz = (bid & 7) * 64 + (bid >> 3);   // 512 blocks, bijective
  int wh  = swz & 1;
  int bh  = swz >> 1;
  int b = bh >> 6, h = bh & 63;
  int w0 = wh * 32;

  // ---- stage B tile: 5 rows x 36 cols x 64 ch, XOR-swizzled ----
  {
    const u16* cbse = comp + (size_t)b * H_ * W_ * CC_;
    for (int i = t; i < 1440; i += 256) {
      int q = i & 7, colr = i >> 3;
      int col = colr % 36, r = colr / 36;
      int hh = h - 2 + r, gw = w0 - 2 + col;
      u32x4 v = {0, 0, 0, 0};
      if ((unsigned)hh < H_ && (unsigned)gw < W_)
        v = *reinterpret_cast<const u32x4*>(cbse + ((size_t)hh * W_ + gw) * CC_ + q * 8);
      int byte = ((r * 36 + col) * 128 + q * 16) ^ ((col & 7) << 4);
      *reinterpret_cast<u32x4*>(lds + byte) = v;
    }
  }
  __syncthreads();   // B ready; no further barriers in K-loop

  int wv    = __builtin_amdgcn_readfirstlane(t >> 6);
  int lane  = t & 63;
  int nlane = lane & 15, kq = lane >> 4;
  int mtbase = (wv < 2) ? wv * 4 : 3 * wv + 2;   // {0,4,8,11}
  int mtcnt  = (wv < 2) ? 4 : 3;

  f32x4 acc[4][2];
  #pragma unroll
  for (int mm = 0; mm < 4; ++mm)
    #pragma unroll
    for (int nt = 0; nt < 2; ++nt) acc[mm][nt] = (f32x4){0.f, 0.f, 0.f, 0.f};

  bf16x8 aA[4], aB[4];
  enc_lda(aA, wfrag, 0, mtbase, mtcnt, lane);
  enc_lda(aB, wfrag, 1, mtbase, mtcnt, lane);
  for (int ks = 0; ks + 2 < 50; ks += 2) {
    enc_step(ks, lds, aA, acc, nlane, kq, mtcnt);
    enc_lda(aA, wfrag, ks + 2, mtbase, mtcnt, lane);
    enc_step(ks + 1, lds, aB, acc, nlane, kq, mtcnt);
    enc_lda(aB, wfrag, ks + 3, mtbase, mtcnt, lane);
  }
  enc_step(48, lds, aA, acc, nlane, kq, mtcnt);
  enc_step(49, lds, aB, acc, nlane, kq, mtcnt);

  // ---- epilogue: logits -> LDS [224][36] f32, fused softmax ----
  __syncthreads();
  float* lg = (float*)lds;
  #pragma unroll
  for (int mm = 0; mm < 4; ++mm) {
    if (mm < mtcnt) {
      #pragma unroll
      for (int nt = 0; nt < 2; ++nt) {
        #pragma unroll
        for (int r = 0; r < 4; ++r) {
          int m  = (mtbase + mm) * 16 + kq * 4 + r;
          int px = nt * 16 + nlane;
          lg[m * 36 + px] = acc[mm][nt][r] + (m < OE_ ? b_enc[m] : 0.f);
        }
      }
    }
  }
  __syncthreads();

  if (t < 128) {
    int px = t & 31, rr = t >> 5;
    float v[49];
    float mx = -1e30f;
    #pragma unroll
    for (int n = 0; n < 49; ++n) {
      v[n] = lg[(4 * n + rr) * 36 + px];
      mx = fmaxf(mx, v[n]);
    }
    float sum = 0.f;
    #pragma unroll
    for (int n = 0; n < 49; ++n) { v[n] = __expf(v[n] - mx); sum += v[n]; }
    float inv = 1.f / sum;
    u16* so = smax + ((size_t)bh * 64 + w0 + px) * OE_;
    #pragma unroll
    for (int n = 0; n < 49; ++n) so[n * 4 + rr] = f2bf(v[n] * inv);   // [n][r] bf16
  }
}

// ------------------------------------------------------------------
// Kernel 3: CARAFE v15 — v14 streaming structure, two fixes:
//  (1) #pragma unroll 1 on dy: live loads = one dy batch (7 b128,
//      28 VGPR) -> total ~90 VGPR -> 5 waves/SIMD of TLP.
//  (2) sv staged in 3.2KB LDS (8 px x 196 bf16): removes 49 global
//      loads/thread; LDS broadcast reads are ~free, occupancy
//      untouched.
// ------------------------------------------------------------------
__global__ __launch_bounds__(256) void carafe_k(
    const u16* __restrict__ xbf, const u16* __restrict__ smax,
    float* __restrict__ out) {
  __shared__ __align__(8) u16 ssm[8 * 200];   // 3,200 B
  int t   = threadIdx.x;
  int bid = blockIdx.x;                      // 2048 blocks
  int pg  = (bid & 7) * 256 + (bid >> 3);    // bijective XCD chunk
  int wq  = pg & 7;
  int h   = (pg >> 3) & 63;
  int b   = pg >> 9;
  int w0  = wq * 8;

  // ---- stage ssm: 8 pixels x 49 b64 quads ----
  for (int idx = t; idx < 392; idx += 256) {
    int pix = idx / 49, n = idx - pix * 49;
    const u16* sp = smax +
        ((size_t)((b * 64 + h) * 64) + w0 + pix) * OE_ + n * 4;
    *reinterpret_cast<u32x2*>(ssm + pix * 200 + n * 4) =
        *reinterpret_cast<const u32x2*>(sp);
  }
  __syncthreads();

  int cg  = t & 31;          // channel group: c = cg*8 .. cg*8+7
  int pix = t >> 5;          // 0..7
  int w   = w0 + pix;
  const u16* sb = ssm + pix * 200;
  const u16* xb = xbf + (size_t)b * H_ * W_ * C_ + cg * 8;

  f32x4 acc[8];
  #pragma unroll
  for (int ci = 0; ci < 8; ++ci) acc[ci] = (f32x4){0.f, 0.f, 0.f, 0.f};

  #pragma unroll 1
  for (int dy = 0; dy < 7; ++dy) {
    int gh = h - 3 + dy;
    bool vr = (unsigned)gh < H_;
    const u16* xrow = xb + (size_t)gh * W_ * C_;
    #pragma unroll
    for (int dx = 0; dx < 7; ++dx) {
      int gw = w - 3 + dx;
      u32x4 xv = {0, 0, 0, 0};
      if (vr && (unsigned)gw < W_)
        xv = *reinterpret_cast<const u32x4*>(xrow + gw * C_);
      u32x2 sv2 = *reinterpret_cast<const u32x2*>(sb + (dy * 7 + dx) * 4);
      f32x4 sv = {__builtin_bit_cast(float, sv2[0] << 16),
                  __builtin_bit_cast(float, sv2[0] & 0xffff0000u),
                  __builtin_bit_cast(float, sv2[1] << 16),
                  __builtin_bit_cast(float, sv2[1] & 0xffff0000u)};
      float xf[8];
      #pragma unroll
      for (int k = 0; k < 4; ++k) {
        xf[2 * k]     = __builtin_bit_cast(float, xv[k] << 16);
        xf[2 * k + 1] = __builtin_bit_cast(float, xv[k] & 0xffff0000u);
      }
      #pragma unroll
      for (int ci = 0; ci < 8; ++ci) {
        acc[ci][0] = fmaf(xf[ci], sv[0], acc[ci][0]);
        acc[ci][1] = fmaf(xf[ci], sv[1], acc[ci][1]);
        acc[ci][2] = fmaf(xf[ci], sv[2], acc[ci][2]);
        acc[ci][3] = fmaf(xf[ci], sv[3], acc[ci][3]);
      }
    }
  }

  #pragma unroll
  for (int ci = 0; ci < 8; ++ci) {
    int c = cg * 8 + ci;
    float* base = out + ((size_t)(b * C_ + c) * OH_ + 2 * h) * OW_ + 2 * w;
    *reinterpret_cast<float2*>(base)       = make_float2(acc[ci][0], acc[ci][1]);
    *reinterpret_cast<float2*>(base + OW_) = make_float2(acc[ci][2], acc[ci][3]);
  }
}

// ------------------------------------------------------------------
extern "C" void kernel_launch(void* const* d_in, const int* in_sizes, int n_in,
                              void* d_out, int out_size, void* d_ws, size_t ws_size,
                              hipStream_t stream) {
  const float* x      = (const float*)d_in[0];
  const float* w_comp = (const float*)d_in[1];
  const float* b_comp = (const float*)d_in[2];
  const float* w_enc  = (const float*)d_in[3];
  const float* b_enc  = (const float*)d_in[4];
  float* out = (float*)d_out;

  float* wct = (float*)d_ws;                    //    16,384 f32
  u16* smax  = (u16*)(wct + 16384);             // 3,211,264 bf16
  u16* wfrag = smax + 3211264;                  //   358,400 bf16
  u16* comp  = wfrag + 358400;                  // 1,048,576 bf16
  u16* xbf   = comp + 1048576;                  // 4,194,304 bf16 (~17.7MB total)

  prep_weights<<<175, 256, 0, stream>>>(w_comp, w_enc, wct, wfrag);
  compress_k<<<B_ * H_ * 4, 256, 0, stream>>>(x, wct, b_comp, comp, xbf);
  enc_mfma_k<<<512, 256, 0, stream>>>(comp, wfrag, b_enc, smax);
  carafe_k<<<2048, 256, 0, stream>>>(xbf, smax, out);
}